// Round 4
// baseline (231.841 us; speedup 1.0000x reference)
//
#include <hip/hip_runtime.h>

// Problem constants
constexpr int Hd = 512;
constexpr int Bd = 64;
constexpr int Sd = 2048;

constexpr int BM = 128;
constexpr int BN = 64;
constexpr int BK = 32;

typedef __bf16 bf16x8 __attribute__((ext_vector_type(8)));
typedef float  f32x4  __attribute__((ext_vector_type(4)));
typedef unsigned short u16x8 __attribute__((ext_vector_type(8)));

__device__ __forceinline__ unsigned short f2bf(float f){
  __bf16 h = (__bf16)f;
  return __builtin_bit_cast(unsigned short, h);
}

__device__ __forceinline__ float fast_tanh(float x){
  // tanh(x) = 1 - 2/(e^{2x}+1); saturates correctly
  float e = __expf(2.0f * x);
  return 1.0f - 2.0f * __builtin_amdgcn_rcpf(e + 1.0f);
}

// XOR-swizzled LDS addressing: rows of 32 bf16 (64B), 16B-granular slots 0..3.
// addr in ushort units. All accesses 16B-aligned; frag reads conflict-free.
__device__ __forceinline__ int swz(int row, int slot){
  return row*32 + ((slot ^ (row & 3)) << 3);
}

// Prologue: blocks [0,128) convert Wr f32->bf16 row-major; blocks [128,192) qproj
__global__ __launch_bounds__(256) void prologue_kernel(const float* __restrict__ Wr,
                                                       unsigned short* __restrict__ Wrb,
                                                       const float* __restrict__ query,
                                                       const float* __restrict__ Wq,
                                                       const float* __restrict__ bq,
                                                       float* __restrict__ qout){
  if (blockIdx.x < 128){
    int base = (blockIdx.x*256 + (int)threadIdx.x) * 8;
    f32x4 v0 = *(const f32x4*)(Wr + base);
    f32x4 v1 = *(const f32x4*)(Wr + base + 4);
    u16x8 o;
    o[0]=f2bf(v0[0]); o[1]=f2bf(v0[1]); o[2]=f2bf(v0[2]); o[3]=f2bf(v0[3]);
    o[4]=f2bf(v1[0]); o[5]=f2bf(v1[1]); o[6]=f2bf(v1[2]); o[7]=f2bf(v1[3]);
    *(u16x8*)(Wrb + base) = o;
  } else {
    int b   = blockIdx.x - 128;
    int tid = threadIdx.x;
    __shared__ float qs[Hd];
    for (int i = tid; i < Hd; i += 256) qs[i] = query[b*Hd + i];
    __syncthreads();
    for (int o = tid; o < Hd; o += 256){
      const float* w = Wq + (size_t)o*Hd;
      float s = 0.f;
      #pragma unroll 4
      for (int k = 0; k < Hd; k += 4){
        f32x4 wv = *(const f32x4*)(w + k);
        s += wv[0]*qs[k] + wv[1]*qs[k+1] + wv[2]*qs[k+2] + wv[3]*qs[k+3];
      }
      qout[b*Hd + o] = s + bq[o];
    }
  }
}

struct SReg { u16x8 a0, a1; f32x4 b0, b1; };

// Per batch b: C[o][s] = sum_h Wr[o][h] * ref[b][s][h]; fused tanh/V logits
__global__ __launch_bounds__(256, 4) void fused_kernel(const float* __restrict__ ref,
                                                       const unsigned short* __restrict__ Wrb,
                                                       const float* __restrict__ br,
                                                       const float* __restrict__ V,
                                                       const float* __restrict__ qbuf,
                                                       float* __restrict__ out,     // [B][H][S]
                                                       float* __restrict__ logits){ // [B][S]
  // Bijective XCD swizzle (nwg=8192 divisible by 8): 4 mt-blocks sharing a ref
  // panel land consecutively on the SAME XCD -> panel fetched from HBM once.
  const int bid = blockIdx.x;
  const int wid = (bid & 7) * (gridDim.x >> 3) + (bid >> 3);
  const int mt  = wid & 3;          // 4 m-tiles of 128
  const int nt  = (wid >> 2) & 31;  // 32 n-tiles of 64
  const int bb  = wid >> 7;
  const int m0  = mt * BM;
  const int n0  = nt * BN;

  const int tid  = threadIdx.x;
  const int lane = tid & 63;
  const int wave = tid >> 6;
  const int wm   = wave >> 1;   // 2x2 wave grid, each wave owns 64x32 of C
  const int wn   = wave & 1;

  __shared__ unsigned short As[BM*32];  // 128 rows x 32 bf16, XOR-swizzled
  __shared__ unsigned short Bs[BN*32];  //  64 rows x 32 bf16, XOR-swizzled

  f32x4 acc[4][2];
  #pragma unroll
  for (int i = 0; i < 4; ++i)
    #pragma unroll
    for (int j = 0; j < 2; ++j)
      acc[i][j] = f32x4{0.f, 0.f, 0.f, 0.f};

  // A staging: thread covers row ar, 16 bf16 (slots s0,s0+1): 2 loads, 2 b128 writes
  const int ar = tid >> 1;
  const int as0 = (tid & 1) * 2;
  // B staging: thread covers row sr, 8 f32 at sk (slot tid&3): 2 loads, 1 b128 write
  const int sr = tid >> 2;
  const int sk = (tid & 3) * 8;

  const unsigned short* Ag = Wrb + (size_t)(m0 + ar)*Hd + as0*8;
  const float*          Bg = ref + ((size_t)bb*Sd + (n0 + sr))*Hd + sk;

  const int aw0 = swz(ar, as0), aw1 = swz(ar, as0 + 1);
  const int bw  = swz(sr, tid & 3);

  const int rofs = lane & 15;
  const int slot = lane >> 4;     // k-slot 0..3 (8 bf16 each)

  SReg S0, S1;

  auto issue = [&](SReg& S, int kt){
    S.a0 = *(const u16x8*)(Ag + kt);
    S.a1 = *(const u16x8*)(Ag + kt + 8);
    S.b0 = *(const f32x4*)(Bg + kt);
    S.b1 = *(const f32x4*)(Bg + kt + 4);
  };
  auto write_stage = [&](const SReg& S){
    *(u16x8*)(&As[aw0]) = S.a0;
    *(u16x8*)(&As[aw1]) = S.a1;
    uint4 pk;
    pk.x = (unsigned)f2bf(S.b0[0]) | ((unsigned)f2bf(S.b0[1]) << 16);
    pk.y = (unsigned)f2bf(S.b0[2]) | ((unsigned)f2bf(S.b0[3]) << 16);
    pk.z = (unsigned)f2bf(S.b1[0]) | ((unsigned)f2bf(S.b1[1]) << 16);
    pk.w = (unsigned)f2bf(S.b1[2]) | ((unsigned)f2bf(S.b1[3]) << 16);
    *(uint4*)(&Bs[bw]) = pk;
  };
  auto halfstep = [&](const SReg& Sw, SReg& Sn, int t){
    write_stage(Sw);                          // stage tile t (regs loaded last halfstep)
    int kn = t + 1; kn = (kn > 15 ? 15 : kn) * BK;
    issue(Sn, kn);                            // prefetch tile t+1, in flight across barrier
    asm volatile("s_waitcnt lgkmcnt(0)" ::: "memory");
    __builtin_amdgcn_s_barrier();
    bf16x8 a[4], b[2];
    #pragma unroll
    for (int mi = 0; mi < 4; ++mi)
      a[mi] = *(const bf16x8*)(&As[swz(wm*64 + mi*16 + rofs, slot)]);
    #pragma unroll
    for (int ni = 0; ni < 2; ++ni)
      b[ni] = *(const bf16x8*)(&Bs[swz(wn*32 + ni*16 + rofs, slot)]);
    #pragma unroll
    for (int mi = 0; mi < 4; ++mi)
      #pragma unroll
      for (int ni = 0; ni < 2; ++ni)
        acc[mi][ni] = __builtin_amdgcn_mfma_f32_16x16x32_bf16(a[mi], b[ni], acc[mi][ni], 0, 0, 0);
    asm volatile("s_waitcnt lgkmcnt(0)" ::: "memory");  // all frag reads done
    __builtin_amdgcn_s_barrier();
  };

  issue(S0, 0);
  #pragma unroll 1
  for (int t2 = 0; t2 < 8; ++t2){
    halfstep(S0, S1, t2*2);
    halfstep(S1, S0, t2*2 + 1);
  }

  // ---- epilogue: +br, NT-store ref_t, fused tanh/V column sums ----
  const int col0 = n0 + wn*32;
  const int row0 = m0 + wm*64;
  const int cl   = lane & 15;          // C/D: col = lane&15
  const int rgrp = (lane >> 4) * 4;    //      row = (lane>>4)*4 + j
  const float* qrow = qbuf + bb*Hd;
  float colsum[2] = {0.f, 0.f};
  float* outb = out + (size_t)bb*Hd*Sd;

  #pragma unroll
  for (int mi = 0; mi < 4; ++mi){
    #pragma unroll
    for (int j = 0; j < 4; ++j){
      int o = row0 + mi*16 + rgrp + j;
      float brv = br[o];
      float qv  = qrow[o];
      float vv  = V[o];
      float* orow = outb + (size_t)o*Sd + col0;
      #pragma unroll
      for (int ni = 0; ni < 2; ++ni){
        float c = acc[mi][ni][j] + brv;
        __builtin_nontemporal_store(c, &orow[ni*16 + cl]);  // don't thrash L2/L3
        colsum[ni] += vv * fast_tanh(qv + c);
      }
    }
  }

  // reduce over the wave's 64 rows: lanes sharing (lane&15) are l, l^16, l^32, l^48
  #pragma unroll
  for (int ni = 0; ni < 2; ++ni){
    colsum[ni] += __shfl_xor(colsum[ni], 16);
    colsum[ni] += __shfl_xor(colsum[ni], 32);
  }
  if (lane < 16){
    float* lrow = logits + (size_t)bb*Sd + col0;
    #pragma unroll
    for (int ni = 0; ni < 2; ++ni)
      atomicAdd(lrow + ni*16 + cl, colsum[ni]);
  }
}

extern "C" void kernel_launch(void* const* d_in, const int* in_sizes, int n_in,
                              void* d_out, int out_size, void* d_ws, size_t ws_size,
                              hipStream_t stream){
  const float* query = (const float*)d_in[0];
  const float* ref   = (const float*)d_in[1];
  const float* Wq    = (const float*)d_in[2];
  const float* bq    = (const float*)d_in[3];
  const float* Wr    = (const float*)d_in[4];
  const float* br    = (const float*)d_in[5];
  const float* V     = (const float*)d_in[6];

  float* out    = (float*)d_out;
  float* logits = out + (size_t)Bd*Hd*Sd;   // second output, concatenated flat
  float* qbuf   = (float*)d_ws;                                      // [B][H] f32 = 128 KB
  unsigned short* Wrb = (unsigned short*)((char*)d_ws + 128*1024);   // [H][H] bf16 = 512 KB

  hipMemsetAsync(logits, 0, (size_t)Bd*Sd*sizeof(float), stream);
  prologue_kernel<<<192, 256, 0, stream>>>(Wr, Wrb, query, Wq, bq, qbuf);

  // grid: 64 batches x (32 n-tiles x 4 m-tiles), XCD-swizzled in-kernel
  fused_kernel<<<Bd*4*32, 256, 0, stream>>>(ref, Wrb, br, V, qbuf, out, logits);
}

// Round 6
// 203.894 us; speedup vs baseline: 1.1371x; 1.1371x over previous
//
#include <hip/hip_runtime.h>

// Problem constants
constexpr int Hd = 512;
constexpr int Bd = 64;
constexpr int Sd = 2048;

constexpr int BM = 128;
constexpr int BN = 128;
constexpr int BK = 32;
constexpr int LDP = BK + 4;   // 72B row stride (proven in r2: modest conflicts, correct)

typedef __bf16 bf16x8 __attribute__((ext_vector_type(8)));
typedef float  f32x4  __attribute__((ext_vector_type(4)));
typedef unsigned short u16x8 __attribute__((ext_vector_type(8)));

__device__ __forceinline__ unsigned short f2bf(float f){
  __bf16 h = (__bf16)f;
  return __builtin_bit_cast(unsigned short, h);
}

__device__ __forceinline__ float fast_tanh(float x){
  // tanh(x) = 1 - 2/(e^{2x}+1); saturates correctly
  float e = __expf(2.0f * x);
  return 1.0f - 2.0f * __builtin_amdgcn_rcpf(e + 1.0f);
}

// Prologue: blocks [0,128) convert Wr f32->bf16 row-major; blocks [128,192) qproj
__global__ __launch_bounds__(256) void prologue_kernel(const float* __restrict__ Wr,
                                                       unsigned short* __restrict__ Wrb,
                                                       const float* __restrict__ query,
                                                       const float* __restrict__ Wq,
                                                       const float* __restrict__ bq,
                                                       float* __restrict__ qout){
  if (blockIdx.x < 128){
    int base = (blockIdx.x*256 + (int)threadIdx.x) * 8;
    f32x4 v0 = *(const f32x4*)(Wr + base);
    f32x4 v1 = *(const f32x4*)(Wr + base + 4);
    u16x8 o;
    o[0]=f2bf(v0[0]); o[1]=f2bf(v0[1]); o[2]=f2bf(v0[2]); o[3]=f2bf(v0[3]);
    o[4]=f2bf(v1[0]); o[5]=f2bf(v1[1]); o[6]=f2bf(v1[2]); o[7]=f2bf(v1[3]);
    *(u16x8*)(Wrb + base) = o;
  } else {
    int b   = blockIdx.x - 128;
    int tid = threadIdx.x;
    __shared__ float qs[Hd];
    for (int i = tid; i < Hd; i += 256) qs[i] = query[b*Hd + i];
    __syncthreads();
    for (int o = tid; o < Hd; o += 256){
      const float* w = Wq + (size_t)o*Hd;
      float s = 0.f;
      #pragma unroll 4
      for (int k = 0; k < Hd; k += 4){
        f32x4 wv = *(const f32x4*)(w + k);
        s += wv[0]*qs[k] + wv[1]*qs[k+1] + wv[2]*qs[k+2] + wv[3]*qs[k+3];
      }
      qout[b*Hd + o] = s + bq[o];
    }
  }
}

struct SReg { u16x8 a0, a1; f32x4 b[4]; };

// Per batch b: C[o][s] = sum_h Wr[o][h] * ref[b][s][h]; fused tanh/V logits
__global__ __launch_bounds__(256, 3) void fused_kernel(const float* __restrict__ ref,
                                                       const unsigned short* __restrict__ Wrb,
                                                       const float* __restrict__ br,
                                                       const float* __restrict__ V,
                                                       const float* __restrict__ qbuf,
                                                       float* __restrict__ out,     // [B][H][S]
                                                       float* __restrict__ logits){ // [B][S]
  // Bijective XCD swizzle (nwg=4096 divisible by 8): 4 mt-blocks sharing a ref
  // panel land consecutively on the SAME XCD -> panel fetched from HBM once.
  const int bid = blockIdx.x;
  const int wid = (bid & 7) * (gridDim.x >> 3) + (bid >> 3);
  const int mt  = wid & 3;
  const int nt  = (wid >> 2) & 15;
  const int bb  = wid >> 6;
  const int m0  = mt * BM;
  const int n0  = nt * BN;

  const int tid  = threadIdx.x;
  const int lane = tid & 63;
  const int wave = tid >> 6;
  const int wm   = wave >> 1;   // 2x2 wave grid, each wave owns 64x64 of C
  const int wn   = wave & 1;

  __shared__ unsigned short As[BM][LDP];
  __shared__ unsigned short Bs[BN][LDP];

  f32x4 acc[4][4];
  #pragma unroll
  for (int i = 0; i < 4; ++i)
    #pragma unroll
    for (int j = 0; j < 4; ++j)
      acc[i][j] = f32x4{0.f, 0.f, 0.f, 0.f};

  // A staging (bf16 source): thread covers row ar, 16 bf16 at ak (two b128 ld/st)
  const int ar = tid >> 1;
  const int ak = (tid & 1) * 16;
  // B staging (f32 source): thread covers rows sr+32*it, 4 f32 at sk
  const int sr = tid >> 3;
  const int sk = (tid & 7) * 4;

  const unsigned short* Ag = Wrb + (size_t)(m0 + ar)*Hd + ak;
  const float*          Bg = ref + ((size_t)bb*Sd + (n0 + sr))*Hd + sk;

  const int rofs = lane & 15;
  const int koff = (lane >> 4) * 8;

  SReg S0, S1;

  auto issue = [&](SReg& S, int kt){
    S.a0 = *(const u16x8*)(Ag + kt);
    S.a1 = *(const u16x8*)(Ag + kt + 8);
    #pragma unroll
    for (int it = 0; it < 4; ++it) S.b[it] = *(const f32x4*)(Bg + (size_t)it*32*Hd + kt);
  };
  auto write_stage = [&](const SReg& S){
    *(u16x8*)(&As[ar][ak])     = S.a0;
    *(u16x8*)(&As[ar][ak + 8]) = S.a1;
    #pragma unroll
    for (int it = 0; it < 4; ++it){
      uint2 pk;
      pk.x = (unsigned)f2bf(S.b[it][0]) | ((unsigned)f2bf(S.b[it][1]) << 16);
      pk.y = (unsigned)f2bf(S.b[it][2]) | ((unsigned)f2bf(S.b[it][3]) << 16);
      *(uint2*)(&Bs[sr + it*32][sk]) = pk;
    }
  };
  // halfstep t: stage tile t (regs issued at t-2), reissue same set for t+2
  auto step = [&](SReg& S, int t){
    write_stage(S);
    int kn = t + 2; kn = (kn > 15 ? 15 : kn) * BK;
    issue(S, kn);                             // dist-2: in flight ~2 halfsteps
    asm volatile("s_waitcnt lgkmcnt(0)" ::: "memory");
    __builtin_amdgcn_s_barrier();
    bf16x8 a[4], b[4];
    #pragma unroll
    for (int mi = 0; mi < 4; ++mi)
      a[mi] = *(const bf16x8*)(&As[wm*64 + mi*16 + rofs][koff]);
    #pragma unroll
    for (int ni = 0; ni < 4; ++ni)
      b[ni] = *(const bf16x8*)(&Bs[wn*64 + ni*16 + rofs][koff]);
    #pragma unroll
    for (int mi = 0; mi < 4; ++mi)
      #pragma unroll
      for (int ni = 0; ni < 4; ++ni)
        acc[mi][ni] = __builtin_amdgcn_mfma_f32_16x16x32_bf16(a[mi], b[ni], acc[mi][ni], 0, 0, 0);
    asm volatile("s_waitcnt lgkmcnt(0)" ::: "memory");  // frag reads done before next writes
    __builtin_amdgcn_s_barrier();
  };

  issue(S0, 0);        // tile 0
  issue(S1, BK);       // tile 1
  #pragma unroll 1
  for (int t2 = 0; t2 < 8; ++t2){
    step(S0, t2*2);
    step(S1, t2*2 + 1);
  }

  // ---- epilogue: +br, NT-store ref_t, fused tanh/V column sums ----
  const int col0 = n0 + wn*64;
  const int row0 = m0 + wm*64;
  const int cl   = lane & 15;          // C/D: col = lane&15
  const int rgrp = (lane >> 4) * 4;    //      row = (lane>>4)*4 + j
  const float* qrow = qbuf + bb*Hd;
  float colsum[4] = {0.f, 0.f, 0.f, 0.f};
  float* outb = out + (size_t)bb*Hd*Sd;

  #pragma unroll
  for (int mi = 0; mi < 4; ++mi){
    #pragma unroll
    for (int j = 0; j < 4; ++j){
      int o = row0 + mi*16 + rgrp + j;
      float brv = br[o];
      float qv  = qrow[o];
      float vv  = V[o];
      float* orow = outb + (size_t)o*Sd + col0;
      #pragma unroll
      for (int ni = 0; ni < 4; ++ni){
        float c = acc[mi][ni][j] + brv;
        __builtin_nontemporal_store(c, &orow[ni*16 + cl]);  // don't thrash L2/L3
        colsum[ni] += vv * fast_tanh(qv + c);
      }
    }
  }

  // reduce over the wave's 64 rows: lanes sharing (lane&15) are l, l^16, l^32, l^48
  #pragma unroll
  for (int ni = 0; ni < 4; ++ni){
    colsum[ni] += __shfl_xor(colsum[ni], 16);
    colsum[ni] += __shfl_xor(colsum[ni], 32);
  }
  if (lane < 16){
    float* lrow = logits + (size_t)bb*Sd + col0;
    #pragma unroll
    for (int ni = 0; ni < 4; ++ni)
      atomicAdd(lrow + ni*16 + cl, colsum[ni]);
  }
}

extern "C" void kernel_launch(void* const* d_in, const int* in_sizes, int n_in,
                              void* d_out, int out_size, void* d_ws, size_t ws_size,
                              hipStream_t stream){
  const float* query = (const float*)d_in[0];
  const float* ref   = (const float*)d_in[1];
  const float* Wq    = (const float*)d_in[2];
  const float* bq    = (const float*)d_in[3];
  const float* Wr    = (const float*)d_in[4];
  const float* br    = (const float*)d_in[5];
  const float* V     = (const float*)d_in[6];

  float* out    = (float*)d_out;
  float* logits = out + (size_t)Bd*Hd*Sd;   // second output, concatenated flat
  float* qbuf   = (float*)d_ws;                                      // [B][H] f32 = 128 KB
  unsigned short* Wrb = (unsigned short*)((char*)d_ws + 128*1024);   // [H][H] bf16 = 512 KB

  hipMemsetAsync(logits, 0, (size_t)Bd*Sd*sizeof(float), stream);
  prologue_kernel<<<192, 256, 0, stream>>>(Wr, Wrb, query, Wq, bq, qbuf);

  // grid: 64 batches x (16 n-tiles x 4 m-tiles), XCD-swizzled in-kernel
  fused_kernel<<<Bd*64, 256, 0, stream>>>(ref, Wrb, br, V, qbuf, out, logits);
}